// Round 9
// baseline (415.070 us; speedup 1.0000x reference)
//
#include <hip/hip_runtime.h>
#include <hip/hip_bf16.h>

// FactorAtt (CoaT) fused pipeline v8, MI355X/gfx950.
// B=8, N=4096, C=768, H=12, D=64.  M_tot = B*N = 32768.
//
// Math: out[b] = q[b] @ M[b] + bp, where
//   Kh = k @ Wk^T (bf16), Vh = v @ Wv^T
//   ctx[b,h,dk,dv] = sum_n softmax_n(Kh)[n,dk] * Vh[n,dv]
//   Gt[b][co][h*64+dk] = sum_dv ctx[b,h,dk,dv] * Wp[co, h*64+dv]
//   Mt[b][co][ci] = sum_kk Gt[b][co][kk] * Wq[kk][ci]
//   out[b][n,co] = sum_ci q[b][n,ci] * Mt[b][co,ci] + bp[co]
// v8: GEMM rewritten as 256x256-tile deep-pipelined kernel (m201-class):
// 8 waves, 24 K-slices of 32, 4 LDS slots (128KB), slice s+3 staged while
// computing s (counted vmcnt(12), never 0 in main loop), raw s_barrier +
// lgkmcnt(0), setprio around MFMA cluster, 2-row-packed XOR-swizzled LDS
// (both-sides; linear gload_lds dest).

typedef __bf16 bf16x8 __attribute__((ext_vector_type(8)));
typedef __bf16 bf16x4 __attribute__((ext_vector_type(4)));
typedef float f32x4 __attribute__((ext_vector_type(4)));

#define GLOAD_LDS16(g, l)                                                        \
  __builtin_amdgcn_global_load_lds(                                              \
      (const __attribute__((address_space(1))) void*)(g),                        \
      (__attribute__((address_space(3))) void*)(l), 16, 0, 0)

__device__ __forceinline__ float bf2f(__hip_bfloat16 h) { return __bfloat162float(h); }

// ---------------------------------------------------------------- casts
__global__ void cast_kernel(const float* __restrict__ src,
                            __bf16* __restrict__ dst, long n) {
  long i = ((long)blockIdx.x * blockDim.x + threadIdx.x) * 4;
  if (i + 3 < n) {
    const float4 f = *(const float4*)(src + i);
    bf16x4 u = {(__bf16)f.x, (__bf16)f.y, (__bf16)f.z, (__bf16)f.w};
    *(bf16x4*)(dst + i) = u;
  }
}

// three tensors of exactly XE elements each
__global__ void cast3_kernel(const float* __restrict__ s0, const float* __restrict__ s1,
                             const float* __restrict__ s2,
                             __bf16* __restrict__ d0, __bf16* __restrict__ d1,
                             __bf16* __restrict__ d2) {
  const float* src = blockIdx.y == 0 ? s0 : (blockIdx.y == 1 ? s1 : s2);
  __bf16* dst = blockIdx.y == 0 ? d0 : (blockIdx.y == 1 ? d1 : d2);
  const long i = ((long)blockIdx.x * blockDim.x + threadIdx.x) * 4;
  const float4 f = *(const float4*)(src + i);
  bf16x4 u = {(__bf16)f.x, (__bf16)f.y, (__bf16)f.z, (__bf16)f.w};
  *(bf16x4*)(dst + i) = u;
}

// dst[ci][kk] = src[kk][ci]  (768x768, fp32 -> bf16)
__global__ void transpose_cast(const float* __restrict__ src,
                               __bf16* __restrict__ dst) {
  __shared__ float tile[32][33];
  const int bx = blockIdx.x * 32, by = blockIdx.y * 32;
  const int tx = threadIdx.x, ty = threadIdx.y;  // 32 x 8
#pragma unroll
  for (int j = 0; j < 32; j += 8)
    tile[ty + j][tx] = src[(long)(bx + ty + j) * 768 + by + tx];
  __syncthreads();
#pragma unroll
  for (int j = 0; j < 32; j += 8)
    dst[(long)(by + ty + j) * 768 + bx + tx] = (__bf16)tile[tx][ty + j];
}

// ---------------------------------------------------------------- GEMM 256x256
// out[m,n] = sum_k A[m,k] * Bt[n,k];  K=768.  512 threads = 8 waves (2x4);
// per-wave output 128x64 (acc[8][4] f32x4).  24 K-slices of 32; slice s in
// LDS slot s&3 (A 16KB + B 16KB per slot; 128KB total).  Pipeline: stage
// slice s+3 while computing s; vmcnt(12) = 3 slices in flight.
// LDS packing: 2 m-rows per 128B LDS-row; 16B chunk swizzle c^((m>>1)&3);
// gload_lds dest linear, global source pre-inverse-swizzled (rule 21).
__global__ __launch_bounds__(512, 2)
void gemm256(const __bf16* __restrict__ Abase,
             const __bf16* __restrict__ Btbase,
             __bf16* __restrict__ outBbase,
             float* __restrict__ outF,
             const float* __restrict__ bias,
             long sAz, long sBz, long sOz, long sBbatch) {
  constexpr int K = 768;
  const int tid = threadIdx.x;
  const int lane = tid & 63;
  const int w = tid >> 6;
  const int wrow = w >> 2;   // 0..1 : rows wrow*128..+127
  const int wcol = w & 3;    // 0..3 : cols wcol*64..+63

  // bijective XCD-chunked swizzle (m204); all grids here are %8==0
  long flat = ((long)blockIdx.z * gridDim.y + blockIdx.y) * gridDim.x + blockIdx.x;
  const long total = (long)gridDim.x * gridDim.y * gridDim.z;
  if ((total & 7) == 0) {
    flat = (flat & 7) * (total >> 3) + (flat >> 3);
  }
  const int bx = (int)(flat % gridDim.x);
  const long rem = flat / gridDim.x;
  const int by = (int)(rem % gridDim.y);
  const int bz = (int)(rem / gridDim.y);

  const int z = bz;
  const int m0 = by * 256;
  const int n0 = bx * 256;

  const __bf16* A = Abase + (long)z * sAz;
  const __bf16* Bt = Btbase + (long)z * sBz + (long)(m0 >> 12) * sBbatch;

  __shared__ __align__(16) __bf16 ldsA[4][128 * 64];  // 4 x 16KB
  __shared__ __align__(16) __bf16 ldsB[4][128 * 64];  // 4 x 16KB

  f32x4 acc[8][4] = {};

  // ---- staging lane map (per issue p in {0,1}):
  //   m = p*128 + w*16 + (lane>>3)*2 + ((lane>>2)&1)
  //   logical 16B chunk c = (lane&3) ^ ((lane>>3)&3)
  //   LDS dest element = p*4096 + w*512 + lane*8   (linear per wave)
  const int sm = w * 16 + ((lane >> 3) << 1) + ((lane >> 2) & 1);
  const int sc = (lane & 3) ^ ((lane >> 3) & 3);
  const __bf16* gA = A + (long)(m0 + sm) * K + sc * 8;
  const __bf16* gB = Bt + (long)(n0 + sm) * K + sc * 8;
  const int ldst = w * 512 + lane * 8;

  auto STAGE = [&](int slot, int ks) {
#pragma unroll
    for (int p = 0; p < 2; ++p)
      GLOAD_LDS16(gA + ks + (long)p * 128 * K, &ldsA[slot][p * 4096 + ldst]);
#pragma unroll
    for (int p = 0; p < 2; ++p)
      GLOAD_LDS16(gB + ks + (long)p * 128 * K, &ldsB[slot][p * 4096 + ldst]);
  };

  // ---- frag-read bases: element idx(m, c) = (m>>1)*64 + (m&1)*32 + (c^((m>>1)&3))*8
  const int rsel = lane & 15;
  const int ck = lane >> 4;            // logical chunk 0..3 (k = ck*8 + j)
  const int swk = (rsel >> 1) & 3;
  const int abase = (wrow * 64 + (rsel >> 1)) * 64 + (rsel & 1) * 32 + ((ck ^ swk) << 3);
  const int bbase = (wcol * 32 + (rsel >> 1)) * 64 + (rsel & 1) * 32 + ((ck ^ swk) << 3);

  // ---- pipeline
  STAGE(0, 0);
  STAGE(1, 32);
  STAGE(2, 64);
#pragma unroll 1
  for (int s = 0; s < 24; ++s) {
    if (s < 21) {
      STAGE((s + 3) & 3, (s + 3) * 32);
      asm volatile("s_waitcnt vmcnt(12)" ::: "memory");
    } else if (s == 21) {
      asm volatile("s_waitcnt vmcnt(8)" ::: "memory");
    } else if (s == 22) {
      asm volatile("s_waitcnt vmcnt(4)" ::: "memory");
    } else {
      asm volatile("s_waitcnt vmcnt(0)" ::: "memory");
    }
    __builtin_amdgcn_sched_barrier(0);
    __builtin_amdgcn_s_barrier();   // slice s ready in slot s&3 (all waves)

    const __bf16* As = ldsA[s & 3];
    const __bf16* Bs = ldsB[s & 3];
    bf16x8 af[8], bf[4];
#pragma unroll
    for (int i = 0; i < 8; ++i) af[i] = *(const bf16x8*)&As[abase + i * 512];
#pragma unroll
    for (int j = 0; j < 4; ++j) bf[j] = *(const bf16x8*)&Bs[bbase + j * 512];
    __builtin_amdgcn_s_setprio(1);
#pragma unroll
    for (int i = 0; i < 8; ++i)
#pragma unroll
      for (int j = 0; j < 4; ++j)
        acc[i][j] = __builtin_amdgcn_mfma_f32_16x16x32_bf16(af[i], bf[j], acc[i][j], 0, 0, 0);
    __builtin_amdgcn_s_setprio(0);

    asm volatile("s_waitcnt lgkmcnt(0)" ::: "memory");
    __builtin_amdgcn_sched_barrier(0);
    __builtin_amdgcn_s_barrier();   // all waves done reading slot s&3 -> re-stageable
  }

  // ---- epilogue.  C/D layout (m89): col = rsel, row = (lane>>4)*4 + r
  const int r0 = (lane >> 4) * 4;
  if (outF == nullptr) {
    __bf16* outp = outBbase + (long)z * sOz;
#pragma unroll
    for (int i = 0; i < 8; ++i) {
      const int row = m0 + wrow * 128 + i * 16 + r0;
#pragma unroll
      for (int j = 0; j < 4; ++j) {
        const int col = n0 + wcol * 64 + j * 16 + rsel;
#pragma unroll
        for (int r = 0; r < 4; ++r)
          outp[(long)(row + r) * 768 + col] = (__bf16)acc[i][j][r];
      }
    }
  } else {
#pragma unroll
    for (int i = 0; i < 8; ++i) {
      const int row = m0 + wrow * 128 + i * 16 + r0;
#pragma unroll
      for (int j = 0; j < 4; ++j) {
        const int col = n0 + wcol * 64 + j * 16 + rsel;
        const float bv = bias[col];
#pragma unroll
        for (int r = 0; r < 4; ++r)
          outF[(long)(row + r) * 768 + col] = acc[i][j][r] + bv;
      }
    }
  }
}

// ---------------------------------------------------------------- ctx partials
__global__ __launch_bounds__(256)
void ctx_partial(const __hip_bfloat16* __restrict__ Kh,
                 const __hip_bfloat16* __restrict__ Vh,
                 float* __restrict__ Upart, float* __restrict__ Spart) {
  const int bh = blockIdx.y, chunk = blockIdx.x;
  const int b = bh / 12, h = bh % 12;
  const int t = threadIdx.x;
  const int rr = t >> 6, d = t & 63;
  const int tdk = (t & 15) * 4, tdv = (t >> 4) * 4;
  __shared__ float ek[4][64];
  __shared__ float vv[4][64];
  __shared__ float sred[256];
  f32x4 U[4] = {};
  float myS = 0.f;
  const long base = ((long)b * 4096 + (long)chunk * 512) * 768 + h * 64 + d;
  for (int r4 = 0; r4 < 128; ++r4) {
    const long off = base + (long)(r4 * 4 + rr) * 768;
    const float e = __expf(bf2f(Kh[off]));
    ek[rr][d] = e;
    myS += e;
    vv[rr][d] = bf2f(Vh[off]);
    __syncthreads();
#pragma unroll
    for (int q = 0; q < 4; ++q) {
      const f32x4 a = *(const f32x4*)&ek[q][tdk];
      const f32x4 vx = *(const f32x4*)&vv[q][tdv];
      U[0] += a[0] * vx;
      U[1] += a[1] * vx;
      U[2] += a[2] * vx;
      U[3] += a[3] * vx;
    }
    __syncthreads();
  }
  float* Ub = Upart + (long)(bh * 8 + chunk) * 4096;
#pragma unroll
  for (int i = 0; i < 4; ++i) *(f32x4*)&Ub[(tdk + i) * 64 + tdv] = U[i];
  sred[t] = myS;
  __syncthreads();
  if (t < 64) {
    const float s = sred[t] + sred[t + 64] + sred[t + 128] + sred[t + 192];
    Spart[(long)(bh * 8 + chunk) * 64 + t] = s;
  }
}

__global__ __launch_bounds__(256)
void ctx_reduce(const float* __restrict__ Upart, const float* __restrict__ Spart,
                float* __restrict__ ctx) {
  const int bh = blockIdx.x;
  const int t = threadIdx.x;
  const int tdk = (t & 15) * 4, tdv = (t >> 4) * 4;
  __shared__ float S[64];
  if (t < 64) {
    float s = 0.f;
#pragma unroll
    for (int c = 0; c < 8; ++c) s += Spart[(long)(bh * 8 + c) * 64 + t];
    S[t] = s;
  }
  __syncthreads();
#pragma unroll
  for (int i = 0; i < 4; ++i) {
    const int dk = tdk + i;
    f32x4 u = {};
#pragma unroll
    for (int c = 0; c < 8; ++c)
      u += *(const f32x4*)&Upart[(long)(bh * 8 + c) * 4096 + dk * 64 + tdv];
    u *= (1.f / S[dk]);
    *(f32x4*)&ctx[(long)bh * 4096 + dk * 64 + tdv] = u;
  }
}

// ---------------------------------------------------------------- G matrix
// Gt[b][co][h*64+dk] = sum_dv ctx[b,h,dk,dv] * Wp[co, h*64+dv]   (bf16 out)
__global__ __launch_bounds__(256, 2)
void gstack(const float* __restrict__ ctx, const float* __restrict__ Wp,
            __bf16* __restrict__ Gt) {
  const int cc = blockIdx.x, h = blockIdx.y, b = blockIdx.z;
  const int t = threadIdx.x, lane = t & 63, w = t >> 6;
  const int co0 = cc * 192;
  __shared__ __align__(16) float wf[192 * 64];  // 48 KB

#pragma unroll
  for (int i = 0; i < 12; ++i) {
    const int flat = i * 256 + t;
    const int r = flat >> 4, c4 = flat & 15;
    const f32x4 vsrc = *(const f32x4*)&Wp[(long)(co0 + r) * 768 + h * 64 + c4 * 4];
    *(f32x4*)&wf[r * 64 + c4 * 4] = vsrc;
  }

  f32x4 cx[16];
  const float* crow = ctx + ((long)(b * 12 + h) * 64 + lane) * 64;
#pragma unroll
  for (int j = 0; j < 16; ++j) cx[j] = *(const f32x4*)&crow[j * 4];

  __syncthreads();

  __bf16* gout = Gt + ((long)(b * 768 + co0 + w * 48) * 768) + h * 64 + lane;
  for (int co = 0; co < 48; ++co) {
    const float* wrow = &wf[(w * 48 + co) * 64];
    f32x4 acc = {};
#pragma unroll
    for (int j = 0; j < 16; ++j) acc += cx[j] * *(const f32x4*)&wrow[j * 4];
    const float s = acc[0] + acc[1] + acc[2] + acc[3];
    gout[(long)co * 768] = (__bf16)s;
  }
}

// ---------------------------------------------------------------- launch
extern "C" void kernel_launch(void* const* d_in, const int* in_sizes, int n_in,
                              void* d_out, int out_size, void* d_ws, size_t ws_size,
                              hipStream_t stream) {
  (void)in_sizes; (void)n_in; (void)out_size; (void)ws_size;
  const float* q = (const float*)d_in[0];
  const float* k = (const float*)d_in[1];
  const float* v = (const float*)d_in[2];
  const float* Wq = (const float*)d_in[3];
  const float* Wk = (const float*)d_in[4];
  const float* Wv = (const float*)d_in[5];
  const float* Wp = (const float*)d_in[6];
  const float* bp = (const float*)d_in[7];
  float* out = (float*)d_out;

  const long XE = 32768L * 768L;
  const long WE = 768L * 768L;

  char* ws = (char*)d_ws;
  __bf16* Kb = (__bf16*)ws;                              // XE bf16 (cast k)
  __bf16* Vb = Kb + XE;                                  // XE bf16 (cast v)
  __bf16* Qb = Vb + XE;                                  // XE bf16 (cast q)
  __bf16* Khb = Qb + XE;                                 // XE bf16
  __bf16* Vhb = Khb + XE;                                // XE bf16
  __bf16* Wb = Vhb + XE;                                 // 4*WE bf16: Wk,Wv,(spare),WqT
  __bf16* Gt = Wb + 4 * WE;                              // 8*WE bf16
  __bf16* Mt = Gt + 8 * WE;                              // 8*WE bf16
  float* Upart = (float*)(Mt + 8 * WE);                  // 96*8*4096 f32
  float* Spart = Upart + 96L * 8 * 4096;                 // 96*8*64 f32
  float* ctx = Spart + 96L * 8 * 64;                     // 96*4096 f32

  // 1) weight casts (tiny) + activation casts (one z=3 streaming dispatch)
  cast_kernel<<<576, 256, 0, stream>>>(Wk, Wb + 0 * WE, WE);
  cast_kernel<<<576, 256, 0, stream>>>(Wv, Wb + 1 * WE, WE);
  transpose_cast<<<dim3(24, 24), dim3(32, 8), 0, stream>>>(Wq, Wb + 3 * WE);  // WqT
  cast3_kernel<<<dim3(24576, 3), 256, 0, stream>>>(k, v, q, Kb, Vb, Qb);

  // 2) K/V projections (z=2): Kh = Kb@Wk^T, Vh = Vb@Wv^T  (bf16 out)
  gemm256<<<dim3(3, 128, 2), 512, 0, stream>>>(Kb, Wb, Khb, nullptr, nullptr,
                                               XE, WE, XE, 0);

  // 3) softmax-weighted context
  ctx_partial<<<dim3(8, 96), 256, 0, stream>>>((const __hip_bfloat16*)Khb,
                                               (const __hip_bfloat16*)Vhb, Upart, Spart);
  ctx_reduce<<<96, 256, 0, stream>>>(Upart, Spart, ctx);

  // 4) Gt[b] = (ctx @ Wp-blocks)^T   (bf16, per batch; fp32 Wp direct)
  gstack<<<dim3(4, 12, 8), 256, 0, stream>>>(ctx, Wp, Gt);

  // 5) Mt[b] : out[m=co, n=ci] = sum_k Gt[co,k] * WqT[ci,k]
  gemm256<<<dim3(3, 3, 8), 512, 0, stream>>>(Gt, Wb + 3 * WE, Mt, nullptr,
                                             nullptr, WE, 0, WE, 0);

  // 6) out[b] = Qb[b] @ Mt[b]^T + bp  (fp32 out)
  gemm256<<<dim3(3, 128, 1), 512, 0, stream>>>(Qb, Mt, nullptr, out,
                                               bp, 0, 0, 0, WE);
}

// Round 10
// 372.054 us; speedup vs baseline: 1.1156x; 1.1156x over previous
//
#include <hip/hip_runtime.h>
#include <hip/hip_bf16.h>

// FactorAtt (CoaT) fused pipeline v9, MI355X/gfx950.
// B=8, N=4096, C=768, H=12, D=64.  M_tot = B*N = 32768.
//
// Math: out[b] = q[b] @ M[b] + bp, where
//   Kh = k @ Wk^T (bf16), Vh = v @ Wv^T
//   ctx[b,h,dk,dv] = sum_n softmax_n(Kh)[n,dk] * Vh[n,dv]
//   Gt[b][co][h*64+dk] = sum_dv ctx[b,h,dk,dv] * Wp[co, h*64+dv]
//   Mt[b][co][ci] = sum_kk Gt[b][co][kk] * Wq[kk][ci]
//   out[b][n,co] = sum_ci q[b][n,ci] * Mt[b][co,ci] + bp[co]
// v9: gemm256 = faithful m201 8-phase schedule. Per 4-phase group (K-tile u):
// quadrant MFMA clusters; stages A-hi(u+1)@p0, B-lo(u+2)@p2, B-hi/A-lo(u+2)@p3;
// vmcnt(6) once per group (3 half-tiles in flight, never drained in main loop);
// 2 raw s_barriers/phase + sched_barrier fences + lgkmcnt(0) + setprio.
// LDS 128KB = 2dbuf x 2half x [128][64] x {A,B}, chunk-XOR swizzle (verified
// 0-conflict in v7/v8).  Mt GEMM keeps the v7 128^2 kernel (grid-fill).

typedef __bf16 bf16x8 __attribute__((ext_vector_type(8)));
typedef __bf16 bf16x4 __attribute__((ext_vector_type(4)));
typedef float f32x4 __attribute__((ext_vector_type(4)));

#define GLOAD_LDS16(g, l)                                                        \
  __builtin_amdgcn_global_load_lds(                                              \
      (const __attribute__((address_space(1))) void*)(g),                        \
      (__attribute__((address_space(3))) void*)(l), 16, 0, 0)

// phase sync: barrier then wait local reads, fully fenced (rule 18)
#define PH_SYNC1                                                                 \
  do {                                                                           \
    __builtin_amdgcn_sched_barrier(0);                                           \
    __builtin_amdgcn_s_barrier();                                                \
    asm volatile("s_waitcnt lgkmcnt(0)" ::: "memory");                           \
    __builtin_amdgcn_sched_barrier(0);                                           \
  } while (0)
#define PH_SYNC2                                                                 \
  do {                                                                           \
    __builtin_amdgcn_sched_barrier(0);                                           \
    __builtin_amdgcn_s_barrier();                                                \
    __builtin_amdgcn_sched_barrier(0);                                           \
  } while (0)

__device__ __forceinline__ float bf2f(__hip_bfloat16 h) { return __bfloat162float(h); }

// ---------------------------------------------------------------- casts
__global__ void cast_kernel(const float* __restrict__ src,
                            __bf16* __restrict__ dst, long n) {
  long i = ((long)blockIdx.x * blockDim.x + threadIdx.x) * 4;
  if (i + 3 < n) {
    const float4 f = *(const float4*)(src + i);
    bf16x4 u = {(__bf16)f.x, (__bf16)f.y, (__bf16)f.z, (__bf16)f.w};
    *(bf16x4*)(dst + i) = u;
  }
}

__global__ void cast3_kernel(const float* __restrict__ s0, const float* __restrict__ s1,
                             const float* __restrict__ s2,
                             __bf16* __restrict__ d0, __bf16* __restrict__ d1,
                             __bf16* __restrict__ d2) {
  const float* src = blockIdx.y == 0 ? s0 : (blockIdx.y == 1 ? s1 : s2);
  __bf16* dst = blockIdx.y == 0 ? d0 : (blockIdx.y == 1 ? d1 : d2);
  const long i = ((long)blockIdx.x * blockDim.x + threadIdx.x) * 4;
  const float4 f = *(const float4*)(src + i);
  bf16x4 u = {(__bf16)f.x, (__bf16)f.y, (__bf16)f.z, (__bf16)f.w};
  *(bf16x4*)(dst + i) = u;
}

// dst[ci][kk] = src[kk][ci]  (768x768, fp32 -> bf16)
__global__ void transpose_cast(const float* __restrict__ src,
                               __bf16* __restrict__ dst) {
  __shared__ float tile[32][33];
  const int bx = blockIdx.x * 32, by = blockIdx.y * 32;
  const int tx = threadIdx.x, ty = threadIdx.y;  // 32 x 8
#pragma unroll
  for (int j = 0; j < 32; j += 8)
    tile[ty + j][tx] = src[(long)(bx + ty + j) * 768 + by + tx];
  __syncthreads();
#pragma unroll
  for (int j = 0; j < 32; j += 8)
    dst[(long)(by + ty + j) * 768 + bx + tx] = (__bf16)tile[tx][ty + j];
}

// ---------------------------------------------------------------- GEMM 256x256
// out[m,n] = sum_k A[m,k] * Bt[n,k];  K=768 = 12 K-tiles of 64.
// 512 thr = 8 waves (2 wrow x 4 wcol); wave out 128x64; acc[8][4] f32x4.
__global__ __launch_bounds__(512, 2)
void gemm256(const __bf16* __restrict__ Abase,
             const __bf16* __restrict__ Btbase,
             __bf16* __restrict__ outBbase,
             float* __restrict__ outF,
             const float* __restrict__ bias,
             long sAz, long sBz, long sOz, long sBbatch) {
  constexpr int K = 768;
  const int tid = threadIdx.x;
  const int lane = tid & 63;
  const int w = tid >> 6;
  const int wrow = w >> 2;
  const int wcol = w & 3;

  // bijective XCD-chunked swizzle (m204); grids are %8==0
  long flat = ((long)blockIdx.z * gridDim.y + blockIdx.y) * gridDim.x + blockIdx.x;
  const long total = (long)gridDim.x * gridDim.y * gridDim.z;
  if ((total & 7) == 0) {
    flat = (flat & 7) * (total >> 3) + (flat >> 3);
  }
  const int bx = (int)(flat % gridDim.x);
  const long rem = flat / gridDim.x;
  const int by = (int)(rem % gridDim.y);
  const int bz = (int)(rem / gridDim.y);

  const int z = bz;
  const int m0 = by * 256;
  const int n0 = bx * 256;

  const __bf16* A = Abase + (long)z * sAz;
  const __bf16* Bt = Btbase + (long)z * sBz + (long)(m0 >> 12) * sBbatch;

  // [dbuf][half][128 rows x 64 k]; chunk-XOR swizzled (phys = logical ^ (row&7))
  __shared__ __align__(16) __bf16 ldsA[2][2][128 * 64];  // 64 KB
  __shared__ __align__(16) __bf16 ldsB[2][2][128 * 64];  // 64 KB

  f32x4 acc[8][4] = {};

  // staging source (per lane): row-in-64-group = w*8 + ro, chunk = (lane&7)^ro
  const int ro = lane >> 3;
  const int gck = (lane & 7) ^ ro;
  const __bf16* gA = A + (long)(m0 + w * 8 + ro) * K + gck * 8;
  const __bf16* gB = Bt + (long)(n0 + w * 8 + ro) * K + gck * 8;

  auto SA = [&](int dd, int hh, int t) {  // stage A half-tile (2 gload_lds/thread)
#pragma unroll
    for (int j = 0; j < 2; ++j)
      GLOAD_LDS16(gA + (long)(hh * 128 + j * 64) * K + t * 64,
                  &ldsA[dd][hh][(j * 64 + w * 8) * 64]);
  };
  auto SB = [&](int dd, int hh, int t) {
#pragma unroll
    for (int j = 0; j < 2; ++j)
      GLOAD_LDS16(gB + (long)(hh * 128 + j * 64) * K + t * 64,
                  &ldsB[dd][hh][(j * 64 + w * 8) * 64]);
  };

  const int rsel = lane & 15;
  const int ck = lane >> 4;            // 0..3
  const int brow0 = (wcol & 1) * 64;   // B row base within its half

  // ---- prologue: 7 half-tiles (B0-lo,B0-hi,A0-lo,A0-hi,B1-lo,B1-hi,A1-lo)
  SB(0, 0, 0); SB(0, 1, 0); SA(0, 0, 0); SA(0, 1, 0);
  SB(1, 0, 1); SB(1, 1, 1); SA(1, 0, 1);
  asm volatile("s_waitcnt vmcnt(6)" ::: "memory");  // A0,B0 landed; 3 halves in flight
  PH_SYNC2;

#pragma unroll 1
  for (int u = 0; u < 12; ++u) {
    const int d = u & 1, dn = d ^ 1;
    const __bf16* Ah = &ldsA[d][wrow][0];
    const __bf16* Bh = &ldsB[d][wcol >> 1][0];
    bf16x8 af[8], bf01[4], bf23[4];

    // ========== phase 0: MFMA m0-3 x n0-1 ==========
#pragma unroll
    for (int j = 0; j < 4; ++j) {
      const int row = j * 16 + rsel, sw = row & 7;
      af[j * 2 + 0] = *(const bf16x8*)&Ah[row * 64 + ((ck ^ sw) << 3)];
      af[j * 2 + 1] = *(const bf16x8*)&Ah[row * 64 + (((4 + ck) ^ sw) << 3)];
    }
#pragma unroll
    for (int n = 0; n < 2; ++n) {
      const int row = brow0 + n * 16 + rsel, sw = row & 7;
      bf01[n * 2 + 0] = *(const bf16x8*)&Bh[row * 64 + ((ck ^ sw) << 3)];
      bf01[n * 2 + 1] = *(const bf16x8*)&Bh[row * 64 + (((4 + ck) ^ sw) << 3)];
    }
    if (u + 1 < 12) SA(dn, 1, u + 1);   // A-hi(u+1); A-hi(u-1) freed @p2(u-1)
    PH_SYNC1;
    __builtin_amdgcn_s_setprio(1);
#pragma unroll
    for (int j = 0; j < 4; ++j)
#pragma unroll
      for (int n = 0; n < 2; ++n) {
        acc[j][n] = __builtin_amdgcn_mfma_f32_16x16x32_bf16(af[j * 2 + 0], bf01[n * 2 + 0], acc[j][n], 0, 0, 0);
        acc[j][n] = __builtin_amdgcn_mfma_f32_16x16x32_bf16(af[j * 2 + 1], bf01[n * 2 + 1], acc[j][n], 0, 0, 0);
      }
    __builtin_amdgcn_s_setprio(0);
    PH_SYNC2;

    // ========== phase 1: MFMA m0-3 x n2-3 ==========
#pragma unroll
    for (int n = 0; n < 2; ++n) {
      const int row = brow0 + (2 + n) * 16 + rsel, sw = row & 7;
      bf23[n * 2 + 0] = *(const bf16x8*)&Bh[row * 64 + ((ck ^ sw) << 3)];
      bf23[n * 2 + 1] = *(const bf16x8*)&Bh[row * 64 + (((4 + ck) ^ sw) << 3)];
    }
    PH_SYNC1;
    __builtin_amdgcn_s_setprio(1);
#pragma unroll
    for (int j = 0; j < 4; ++j)
#pragma unroll
      for (int n = 0; n < 2; ++n) {
        acc[j][2 + n] = __builtin_amdgcn_mfma_f32_16x16x32_bf16(af[j * 2 + 0], bf23[n * 2 + 0], acc[j][2 + n], 0, 0, 0);
        acc[j][2 + n] = __builtin_amdgcn_mfma_f32_16x16x32_bf16(af[j * 2 + 1], bf23[n * 2 + 1], acc[j][2 + n], 0, 0, 0);
      }
    __builtin_amdgcn_s_setprio(0);
    PH_SYNC2;

    // ========== phase 2: MFMA m4-7 x n0-1 ==========
#pragma unroll
    for (int j = 0; j < 4; ++j) {
      const int row = (4 + j) * 16 + rsel, sw = row & 7;
      af[j * 2 + 0] = *(const bf16x8*)&Ah[row * 64 + ((ck ^ sw) << 3)];
      af[j * 2 + 1] = *(const bf16x8*)&Ah[row * 64 + (((4 + ck) ^ sw) << 3)];
    }
    if (u + 2 < 12) SB(d, 0, u + 2);    // B-lo(u+2); B(u) freed @p1 barrier
    PH_SYNC1;
    __builtin_amdgcn_s_setprio(1);
#pragma unroll
    for (int j = 0; j < 4; ++j)
#pragma unroll
      for (int n = 0; n < 2; ++n) {
        acc[4 + j][n] = __builtin_amdgcn_mfma_f32_16x16x32_bf16(af[j * 2 + 0], bf01[n * 2 + 0], acc[4 + j][n], 0, 0, 0);
        acc[4 + j][n] = __builtin_amdgcn_mfma_f32_16x16x32_bf16(af[j * 2 + 1], bf01[n * 2 + 1], acc[4 + j][n], 0, 0, 0);
      }
    __builtin_amdgcn_s_setprio(0);
    PH_SYNC2;

    // ========== phase 3: MFMA m4-7 x n2-3 ==========
    if (u + 2 < 12) { SB(d, 1, u + 2); SA(d, 0, u + 2); }  // A-lo(u) freed @p2 barrier
    if (u <= 9) {
      asm volatile("s_waitcnt vmcnt(6)" ::: "memory");     // A(u+1),B(u+1) landed
    } else if (u == 10) {
      asm volatile("s_waitcnt vmcnt(0)" ::: "memory");     // drain for final tile
    }
    PH_SYNC1;
    __builtin_amdgcn_s_setprio(1);
#pragma unroll
    for (int j = 0; j < 4; ++j)
#pragma unroll
      for (int n = 0; n < 2; ++n) {
        acc[4 + j][2 + n] = __builtin_amdgcn_mfma_f32_16x16x32_bf16(af[j * 2 + 0], bf23[n * 2 + 0], acc[4 + j][2 + n], 0, 0, 0);
        acc[4 + j][2 + n] = __builtin_amdgcn_mfma_f32_16x16x32_bf16(af[j * 2 + 1], bf23[n * 2 + 1], acc[4 + j][2 + n], 0, 0, 0);
      }
    __builtin_amdgcn_s_setprio(0);
    PH_SYNC2;
  }

  // ---- epilogue.  C/D layout (m89): col = lane&15, row = (lane>>4)*4 + r
  const int r0 = (lane >> 4) * 4;
  if (outF == nullptr) {
    __bf16* outp = outBbase + (long)z * sOz;
#pragma unroll
    for (int i = 0; i < 8; ++i) {
      const int row = m0 + wrow * 128 + i * 16 + r0;
#pragma unroll
      for (int j = 0; j < 4; ++j) {
        const int col = n0 + wcol * 64 + j * 16 + rsel;
#pragma unroll
        for (int r = 0; r < 4; ++r)
          outp[(long)(row + r) * 768 + col] = (__bf16)acc[i][j][r];
      }
    }
  } else {
#pragma unroll
    for (int i = 0; i < 8; ++i) {
      const int row = m0 + wrow * 128 + i * 16 + r0;
#pragma unroll
      for (int j = 0; j < 4; ++j) {
        const int col = n0 + wcol * 64 + j * 16 + rsel;
        const float bv = bias[col];
#pragma unroll
        for (int r = 0; r < 4; ++r)
          outF[(long)(row + r) * 768 + col] = acc[i][j][r] + bv;
      }
    }
  }
}

// ---------------------------------------------------------------- GEMM 128 (v7)
// Used for the small Mt GEMM only.  BK=64, single-buffered, XOR swizzle.
__global__ __launch_bounds__(256, 2)
void gemm_bt(const __bf16* __restrict__ Abase,
             const __bf16* __restrict__ Btbase,
             __bf16* __restrict__ outBbase,
             float* __restrict__ outF,
             const float* __restrict__ bias,
             long sAz, long sBz, long sOz, long sBbatch) {
  constexpr int K = 768;
  const int tid = threadIdx.x;
  const int lane = tid & 63;
  const int w = tid >> 6;
  const int wr = (w >> 1) * 64;
  const int wc = (w & 1) * 64;

  long flat = ((long)blockIdx.z * gridDim.y + blockIdx.y) * gridDim.x + blockIdx.x;
  const long total = (long)gridDim.x * gridDim.y * gridDim.z;
  if ((total & 7) == 0) {
    flat = (flat & 7) * (total >> 3) + (flat >> 3);
  }
  const int bx = (int)(flat % gridDim.x);
  const long rem = flat / gridDim.x;
  const int by = (int)(rem % gridDim.y);
  const int bz = (int)(rem / gridDim.y);

  const int z = bz;
  const int m0 = by * 128;
  const int n0 = bx * 128;

  const __bf16* A = Abase + (long)z * sAz;
  const __bf16* Bt = Btbase + (long)z * sBz + (long)(m0 >> 12) * sBbatch;

  __shared__ __align__(16) __bf16 As[128 * 64];
  __shared__ __align__(16) __bf16 Bs[128 * 64];

  f32x4 acc[4][4] = {};

  const int ro = lane >> 3;
  const int gck = (lane & 7) ^ ro;
  const __bf16* gA = A + (long)(m0 + w * 8 + ro) * K + gck * 8;
  const __bf16* gB = Bt + (long)(n0 + w * 8 + ro) * K + gck * 8;

  const int rsel = lane & 15;
  const int r7 = rsel & 7;
  const int cseg = lane >> 4;

  for (int k0 = 0; k0 < K; k0 += 64) {
#pragma unroll
    for (int p = 0; p < 4; ++p) {
      GLOAD_LDS16(gA + k0 + (long)p * 32 * K, &As[(p * 32 + w * 8) * 64]);
      GLOAD_LDS16(gB + k0 + (long)p * 32 * K, &Bs[(p * 32 + w * 8) * 64]);
    }
    __syncthreads();

#pragma unroll
    for (int kk = 0; kk < 2; ++kk) {
      const int ckl = kk * 4 + cseg;
      bf16x8 af[4], bfr[4];
#pragma unroll
      for (int i = 0; i < 4; ++i) {
        const int rowa = wr + i * 16 + rsel;
        const int rowb = wc + i * 16 + rsel;
        af[i] = *(const bf16x8*)&As[rowa * 64 + ((ckl ^ r7) << 3)];
        bfr[i] = *(const bf16x8*)&Bs[rowb * 64 + ((ckl ^ r7) << 3)];
      }
#pragma unroll
      for (int i = 0; i < 4; ++i)
#pragma unroll
        for (int j = 0; j < 4; ++j)
          acc[i][j] = __builtin_amdgcn_mfma_f32_16x16x32_bf16(af[i], bfr[j], acc[i][j], 0, 0, 0);
    }
    __syncthreads();
  }

  const int r0 = (lane >> 4) * 4;
  if (outF == nullptr) {
    __bf16* outp = outBbase + (long)z * sOz;
#pragma unroll
    for (int i = 0; i < 4; ++i) {
      const int row = m0 + wr + i * 16 + r0;
#pragma unroll
      for (int j = 0; j < 4; ++j) {
        const int col = n0 + wc + j * 16 + rsel;
#pragma unroll
        for (int r = 0; r < 4; ++r)
          outp[(long)(row + r) * 768 + col] = (__bf16)acc[i][j][r];
      }
    }
  } else {
#pragma unroll
    for (int i = 0; i < 4; ++i) {
      const int row = m0 + wr + i * 16 + r0;
#pragma unroll
      for (int j = 0; j < 4; ++j) {
        const int col = n0 + wc + j * 16 + rsel;
        const float bv = bias[col];
#pragma unroll
        for (int r = 0; r < 4; ++r)
          outF[(long)(row + r) * 768 + col] = acc[i][j][r] + bv;
      }
    }
  }
}

// ---------------------------------------------------------------- ctx partials
__global__ __launch_bounds__(256)
void ctx_partial(const __hip_bfloat16* __restrict__ Kh,
                 const __hip_bfloat16* __restrict__ Vh,
                 float* __restrict__ Upart, float* __restrict__ Spart) {
  const int bh = blockIdx.y, chunk = blockIdx.x;
  const int b = bh / 12, h = bh % 12;
  const int t = threadIdx.x;
  const int rr = t >> 6, d = t & 63;
  const int tdk = (t & 15) * 4, tdv = (t >> 4) * 4;
  __shared__ float ek[4][64];
  __shared__ float vv[4][64];
  __shared__ float sred[256];
  f32x4 U[4] = {};
  float myS = 0.f;
  const long base = ((long)b * 4096 + (long)chunk * 512) * 768 + h * 64 + d;
  for (int r4 = 0; r4 < 128; ++r4) {
    const long off = base + (long)(r4 * 4 + rr) * 768;
    const float e = __expf(bf2f(Kh[off]));
    ek[rr][d] = e;
    myS += e;
    vv[rr][d] = bf2f(Vh[off]);
    __syncthreads();
#pragma unroll
    for (int q = 0; q < 4; ++q) {
      const f32x4 a = *(const f32x4*)&ek[q][tdk];
      const f32x4 vx = *(const f32x4*)&vv[q][tdv];
      U[0] += a[0] * vx;
      U[1] += a[1] * vx;
      U[2] += a[2] * vx;
      U[3] += a[3] * vx;
    }
    __syncthreads();
  }
  float* Ub = Upart + (long)(bh * 8 + chunk) * 4096;
#pragma unroll
  for (int i = 0; i < 4; ++i) *(f32x4*)&Ub[(tdk + i) * 64 + tdv] = U[i];
  sred[t] = myS;
  __syncthreads();
  if (t < 64) {
    const float s = sred[t] + sred[t + 64] + sred[t + 128] + sred[t + 192];
    Spart[(long)(bh * 8 + chunk) * 64 + t] = s;
  }
}

__global__ __launch_bounds__(256)
void ctx_reduce(const float* __restrict__ Upart, const float* __restrict__ Spart,
                float* __restrict__ ctx) {
  const int bh = blockIdx.x;
  const int t = threadIdx.x;
  const int tdk = (t & 15) * 4, tdv = (t >> 4) * 4;
  __shared__ float S[64];
  if (t < 64) {
    float s = 0.f;
#pragma unroll
    for (int c = 0; c < 8; ++c) s += Spart[(long)(bh * 8 + c) * 64 + t];
    S[t] = s;
  }
  __syncthreads();
#pragma unroll
  for (int i = 0; i < 4; ++i) {
    const int dk = tdk + i;
    f32x4 u = {};
#pragma unroll
    for (int c = 0; c < 8; ++c)
      u += *(const f32x4*)&Upart[(long)(bh * 8 + c) * 4096 + dk * 64 + tdv];
    u *= (1.f / S[dk]);
    *(f32x4*)&ctx[(long)bh * 4096 + dk * 64 + tdv] = u;
  }
}

// ---------------------------------------------------------------- G matrix
__global__ __launch_bounds__(256, 2)
void gstack(const float* __restrict__ ctx, const float* __restrict__ Wp,
            __bf16* __restrict__ Gt) {
  const int cc = blockIdx.x, h = blockIdx.y, b = blockIdx.z;
  const int t = threadIdx.x, lane = t & 63, w = t >> 6;
  const int co0 = cc * 192;
  __shared__ __align__(16) float wf[192 * 64];  // 48 KB

#pragma unroll
  for (int i = 0; i < 12; ++i) {
    const int flat = i * 256 + t;
    const int r = flat >> 4, c4 = flat & 15;
    const f32x4 vsrc = *(const f32x4*)&Wp[(long)(co0 + r) * 768 + h * 64 + c4 * 4];
    *(f32x4*)&wf[r * 64 + c4 * 4] = vsrc;
  }

  f32x4 cx[16];
  const float* crow = ctx + ((long)(b * 12 + h) * 64 + lane) * 64;
#pragma unroll
  for (int j = 0; j < 16; ++j) cx[j] = *(const f32x4*)&crow[j * 4];

  __syncthreads();

  __bf16* gout = Gt + ((long)(b * 768 + co0 + w * 48) * 768) + h * 64 + lane;
  for (int co = 0; co < 48; ++co) {
    const float* wrow = &wf[(w * 48 + co) * 64];
    f32x4 acc = {};
#pragma unroll
    for (int j = 0; j < 16; ++j) acc += cx[j] * *(const f32x4*)&wrow[j * 4];
    const float s = acc[0] + acc[1] + acc[2] + acc[3];
    gout[(long)co * 768] = (__bf16)s;
  }
}

// ---------------------------------------------------------------- launch
extern "C" void kernel_launch(void* const* d_in, const int* in_sizes, int n_in,
                              void* d_out, int out_size, void* d_ws, size_t ws_size,
                              hipStream_t stream) {
  (void)in_sizes; (void)n_in; (void)out_size; (void)ws_size;
  const float* q = (const float*)d_in[0];
  const float* k = (const float*)d_in[1];
  const float* v = (const float*)d_in[2];
  const float* Wq = (const float*)d_in[3];
  const float* Wk = (const float*)d_in[4];
  const float* Wv = (const float*)d_in[5];
  const float* Wp = (const float*)d_in[6];
  const float* bp = (const float*)d_in[7];
  float* out = (float*)d_out;

  const long XE = 32768L * 768L;
  const long WE = 768L * 768L;

  char* ws = (char*)d_ws;
  __bf16* Kb = (__bf16*)ws;                              // XE bf16 (cast k)
  __bf16* Vb = Kb + XE;                                  // XE bf16 (cast v)
  __bf16* Qb = Vb + XE;                                  // XE bf16 (cast q)
  __bf16* Khb = Qb + XE;                                 // XE bf16
  __bf16* Vhb = Khb + XE;                                // XE bf16
  __bf16* Wb = Vhb + XE;                                 // 4*WE bf16: Wk,Wv,(spare),WqT
  __bf16* Gt = Wb + 4 * WE;                              // 8*WE bf16
  __bf16* Mt = Gt + 8 * WE;                              // 8*WE bf16
  float* Upart = (float*)(Mt + 8 * WE);                  // 96*8*4096 f32
  float* Spart = Upart + 96L * 8 * 4096;                 // 96*8*64 f32
  float* ctx = Spart + 96L * 8 * 64;                     // 96*4096 f32

  // 1) weight casts + activation casts
  cast_kernel<<<576, 256, 0, stream>>>(Wk, Wb + 0 * WE, WE);
  cast_kernel<<<576, 256, 0, stream>>>(Wv, Wb + 1 * WE, WE);
  transpose_cast<<<dim3(24, 24), dim3(32, 8), 0, stream>>>(Wq, Wb + 3 * WE);  // WqT
  cast3_kernel<<<dim3(24576, 3), 256, 0, stream>>>(k, v, q, Kb, Vb, Qb);

  // 2) K/V projections (z=2): Kh = Kb@Wk^T, Vh = Vb@Wv^T  (bf16 out)
  gemm256<<<dim3(3, 128, 2), 512, 0, stream>>>(Kb, Wb, Khb, nullptr, nullptr,
                                               XE, WE, XE, 0);

  // 3) softmax-weighted context
  ctx_partial<<<dim3(8, 96), 256, 0, stream>>>((const __hip_bfloat16*)Khb,
                                               (const __hip_bfloat16*)Vhb, Upart, Spart);
  ctx_reduce<<<96, 256, 0, stream>>>(Upart, Spart, ctx);

  // 4) Gt[b] = (ctx @ Wp-blocks)^T
  gstack<<<dim3(4, 12, 8), 256, 0, stream>>>(ctx, Wp, Gt);

  // 5) Mt[b] : out[m=co, n=ci] = sum_k Gt[co,k] * WqT[ci,k]   (128^2 kernel)
  gemm_bt<<<dim3(6, 6, 8), 256, 0, stream>>>(Gt, Wb + 3 * WE, Mt, nullptr,
                                             nullptr, WE, 0, WE, 0);

  // 6) out[b] = Qb[b] @ Mt[b]^T + bp  (fp32 out)
  gemm256<<<dim3(3, 128, 1), 512, 0, stream>>>(Qb, Mt, nullptr, out,
                                               bp, 0, 0, 0, WE);
}

// Round 11
// 299.651 us; speedup vs baseline: 1.3852x; 1.2416x over previous
//
#include <hip/hip_runtime.h>
#include <hip/hip_bf16.h>

// FactorAtt (CoaT) fused pipeline v10, MI355X/gfx950.
// B=8, N=4096, C=768, H=12, D=64.  M_tot = B*N = 32768.
//
// Math: out[b] = q[b] @ M[b] + bp, where
//   Kh = k @ Wk^T (bf16), Vh = v @ Wv^T
//   ctx[b,h,dk,dv] = sum_n softmax_n(Kh)[n,dk] * Vh[n,dv]
//   Gt[b][co][h*64+dk] = sum_dv ctx[b,h,dk,dv] * Wp[co, h*64+dv]
//   Mt[b][co][ci] = sum_kk Gt[b][co][kk] * Wq[kk][ci]
//   out[b][n,co] = sum_ci q[b][n,ci] * Mt[b][co,ci] + bp[co]
// v10: GEMM = frozen v7 structure (BK=64, single-buffer, XOR swizzle; best of
// 5 schedule attempts).  NEW: (a) AF32 A-staging — q/k/v read fp32 directly,
// cast at LDS->frag (kills the 72us cast3 kernel); chunk swizzle
// phys = logical ^ (row&15) both-sides, linear gload_lds dest.
// (b) ctx_partial: 32-row LDS tiles, 32 barriers instead of 256.

typedef __bf16 bf16x8 __attribute__((ext_vector_type(8)));
typedef __bf16 bf16x4 __attribute__((ext_vector_type(4)));
typedef float f32x4 __attribute__((ext_vector_type(4)));

#define GLOAD_LDS16(g, l)                                                        \
  __builtin_amdgcn_global_load_lds(                                              \
      (const __attribute__((address_space(1))) void*)(g),                        \
      (__attribute__((address_space(3))) void*)(l), 16, 0, 0)

__device__ __forceinline__ float bf2f(__hip_bfloat16 h) { return __bfloat162float(h); }

// ---------------------------------------------------------------- casts (weights)
__global__ void cast_kernel(const float* __restrict__ src,
                            __bf16* __restrict__ dst, long n) {
  long i = ((long)blockIdx.x * blockDim.x + threadIdx.x) * 4;
  if (i + 3 < n) {
    const float4 f = *(const float4*)(src + i);
    bf16x4 u = {(__bf16)f.x, (__bf16)f.y, (__bf16)f.z, (__bf16)f.w};
    *(bf16x4*)(dst + i) = u;
  }
}

// dst[ci][kk] = src[kk][ci]  (768x768, fp32 -> bf16)
__global__ void transpose_cast(const float* __restrict__ src,
                               __bf16* __restrict__ dst) {
  __shared__ float tile[32][33];
  const int bx = blockIdx.x * 32, by = blockIdx.y * 32;
  const int tx = threadIdx.x, ty = threadIdx.y;  // 32 x 8
#pragma unroll
  for (int j = 0; j < 32; j += 8)
    tile[ty + j][tx] = src[(long)(bx + ty + j) * 768 + by + tx];
  __syncthreads();
#pragma unroll
  for (int j = 0; j < 32; j += 8)
    dst[(long)(by + ty + j) * 768 + bx + tx] = (__bf16)tile[tx][ty + j];
}

// ---------------------------------------------------------------- GEMM (B^T form)
// out[m,n] = sum_k A[m,k] * Bt[n,k];  K=768, tiles 128x128, BK=64, 4 waves.
// v7 structure: single-buffered LDS, 2 barriers per K-step, 12 K-steps.
// AF32: A fp32 in global; LDS A = [128][64] f32, 16B-chunk swizzle
//   phys = logical ^ (row&15); cast to bf16 at frag build.
// bf16: LDS A = [128][64] bf16, 8-chunk swizzle phys = logical ^ (row&7).
// A2 != nullptr: z==1 selects A2 (z-stride disabled).
template <bool AF32>
__global__ __launch_bounds__(256, 2)
void gemm_bt(const void* __restrict__ Abase_, const void* __restrict__ A2,
             const __bf16* __restrict__ Btbase,
             __bf16* __restrict__ outBbase,
             float* __restrict__ outF,
             const float* __restrict__ bias,
             long sAz, long sBz, long sOz, long sBbatch) {
  constexpr int K = 768;
  const int tid = threadIdx.x;
  const int lane = tid & 63;
  const int w = tid >> 6;
  const int wr = (w >> 1) * 64;
  const int wc = (w & 1) * 64;

  // bijective XCD-chunked swizzle (m204)
  long flat = ((long)blockIdx.z * gridDim.y + blockIdx.y) * gridDim.x + blockIdx.x;
  const long total = (long)gridDim.x * gridDim.y * gridDim.z;
  if ((total & 7) == 0) {
    flat = (flat & 7) * (total >> 3) + (flat >> 3);
  }
  const int bx = (int)(flat % gridDim.x);
  const long rem = flat / gridDim.x;
  const int by = (int)(rem % gridDim.y);
  const int bz = (int)(rem / gridDim.y);

  const int z = bz;
  const int m0 = by * 128;
  const int n0 = bx * 128;

  const __bf16* Bt = Btbase + (long)z * sBz + (long)(m0 >> 12) * sBbatch;

  __shared__ __align__(16) float AsF[AF32 ? 128 * 64 : 8];   // 32 KB (AF32)
  __shared__ __align__(16) __bf16 AsB[AF32 ? 8 : 128 * 64];  // 16 KB (bf16)
  __shared__ __align__(16) __bf16 Bs[128 * 64];              // 16 KB

  f32x4 acc[4][4] = {};

  // ---- B staging (v7): 4 issues; issue p rows p*32 + w*8 + ro; chunk (lane&7)^ro
  const int ro = lane >> 3;
  const int gck = (lane & 7) ^ ro;
  const __bf16* gB = Bt + (long)(n0 + w * 8 + ro) * K + gck * 8;

  // ---- A staging
  const void* Asel = (A2 != nullptr && z == 1) ? A2 : Abase_;
  const long az = (A2 == nullptr) ? (long)z * sAz : 0;
  const float* gAf = nullptr;
  const __bf16* gAb = nullptr;
  if constexpr (AF32) {
    // 8 issues; issue p rows p*16 + (tid>>4); logical chunk (tid&15)^(tid>>4)
    const int arow = tid >> 4;
    const int ach = (tid & 15) ^ arow;
    gAf = (const float*)Asel + az + (long)(m0 + arow) * K + ach * 4;
  } else {
    gAb = (const __bf16*)Asel + az + (long)(m0 + w * 8 + ro) * K + gck * 8;
  }

  const int rsel = lane & 15;
  const int r7 = rsel & 7;
  const int cseg = lane >> 4;  // 0..3

  for (int k0 = 0; k0 < K; k0 += 64) {
    if constexpr (AF32) {
#pragma unroll
      for (int p = 0; p < 8; ++p)
        GLOAD_LDS16(gAf + k0 + (long)p * 16 * K, &AsF[p * 1024 + w * 256]);
#pragma unroll
      for (int p = 0; p < 4; ++p)
        GLOAD_LDS16(gB + k0 + (long)p * 32 * K, &Bs[(p * 32 + w * 8) * 64]);
    } else {
#pragma unroll
      for (int p = 0; p < 4; ++p) {
        GLOAD_LDS16(gAb + k0 + (long)p * 32 * K, &AsB[(p * 32 + w * 8) * 64]);
        GLOAD_LDS16(gB + k0 + (long)p * 32 * K, &Bs[(p * 32 + w * 8) * 64]);
      }
    }
    __syncthreads();

#pragma unroll
    for (int kk = 0; kk < 2; ++kk) {
      bf16x8 af[4], bfr[4];
#pragma unroll
      for (int i = 0; i < 4; ++i) {
        const int rowa = wr + i * 16 + rsel;   // rowa & 15 == rsel
        const int rowb = wc + i * 16 + rsel;
        if constexpr (AF32) {
          const int c0 = kk * 8 + cseg * 2;    // logical f32-chunk (even)
          const f32x4 lo = *(const f32x4*)&AsF[rowa * 64 + ((c0 ^ rsel) << 2)];
          const f32x4 hi = *(const f32x4*)&AsF[rowa * 64 + (((c0 + 1) ^ rsel) << 2)];
          bf16x8 a = {(__bf16)lo[0], (__bf16)lo[1], (__bf16)lo[2], (__bf16)lo[3],
                      (__bf16)hi[0], (__bf16)hi[1], (__bf16)hi[2], (__bf16)hi[3]};
          af[i] = a;
        } else {
          const int ckl = kk * 4 + cseg;       // logical bf16-chunk
          af[i] = *(const bf16x8*)&AsB[rowa * 64 + ((ckl ^ r7) << 3)];
        }
        const int ckl = kk * 4 + cseg;
        bfr[i] = *(const bf16x8*)&Bs[rowb * 64 + ((ckl ^ r7) << 3)];
      }
#pragma unroll
      for (int i = 0; i < 4; ++i)
#pragma unroll
        for (int j = 0; j < 4; ++j)
          acc[i][j] = __builtin_amdgcn_mfma_f32_16x16x32_bf16(af[i], bfr[j], acc[i][j], 0, 0, 0);
    }
    __syncthreads();
  }

  // C/D layout (m89): col = lane&15, row = (lane>>4)*4 + r
  const int r0 = (lane >> 4) * 4;
  if (outF == nullptr) {
    __bf16* outp = outBbase + (long)z * sOz;
#pragma unroll
    for (int i = 0; i < 4; ++i) {
      const int row = m0 + wr + i * 16 + r0;
#pragma unroll
      for (int j = 0; j < 4; ++j) {
        const int col = n0 + wc + j * 16 + rsel;
#pragma unroll
        for (int r = 0; r < 4; ++r)
          outp[(long)(row + r) * 768 + col] = (__bf16)acc[i][j][r];
      }
    }
  } else {
#pragma unroll
    for (int i = 0; i < 4; ++i) {
      const int row = m0 + wr + i * 16 + r0;
#pragma unroll
      for (int j = 0; j < 4; ++j) {
        const int col = n0 + wc + j * 16 + rsel;
        const float bv = bias[col];
#pragma unroll
        for (int r = 0; r < 4; ++r)
          outF[(long)(row + r) * 768 + col] = acc[i][j][r] + bv;
      }
    }
  }
}

// ---------------------------------------------------------------- ctx partials
// Per (b,h), n-chunk of 512: U[dk,dv] += exp(Kh[n,dk]) * Vh[n,dv]; S[dk] += exp.
// v10: 32-row LDS tiles (16 iters x 2 barriers, was 128 x 2); coalesced bf16x8
// stage loads; wave 0 accumulates S.
__global__ __launch_bounds__(256)
void ctx_partial(const __bf16* __restrict__ Kh,
                 const __bf16* __restrict__ Vh,
                 float* __restrict__ Upart, float* __restrict__ Spart) {
  const int bh = blockIdx.y, chunk = blockIdx.x;
  const int b = bh / 12, h = bh % 12;
  const int t = threadIdx.x;
  const int tdk = (t & 15) * 4, tdv = (t >> 4) * 4;
  const int sr = t >> 3, sc = (t & 7) * 8;  // stage role: row 0..31, col-octet
  __shared__ float ek[32][64];
  __shared__ float vv[32][64];
  f32x4 U[4] = {};
  float sacc = 0.f;  // wave 0 (t<64): column-t running sum
  const long base = ((long)b * 4096 + (long)chunk * 512) * 768 + h * 64;
#pragma unroll 1
  for (int it = 0; it < 16; ++it) {
    const long roff = base + (long)(it * 32 + sr) * 768 + sc;
    const bf16x8 kb = *(const bf16x8*)(Kh + roff);
    const bf16x8 vb = *(const bf16x8*)(Vh + roff);
    __syncthreads();  // prior readers of ek/vv done
#pragma unroll
    for (int j = 0; j < 8; ++j) {
      ek[sr][sc + j] = __expf((float)kb[j]);
      vv[sr][sc + j] = (float)vb[j];
    }
    __syncthreads();  // tile staged
#pragma unroll 4
    for (int r = 0; r < 32; ++r) {
      const f32x4 a = *(const f32x4*)&ek[r][tdk];
      const f32x4 vx = *(const f32x4*)&vv[r][tdv];
      U[0] += a[0] * vx;
      U[1] += a[1] * vx;
      U[2] += a[2] * vx;
      U[3] += a[3] * vx;
    }
    if (t < 64) {
#pragma unroll 4
      for (int r = 0; r < 32; ++r) sacc += ek[r][t];
    }
  }
  float* Ub = Upart + (long)(bh * 8 + chunk) * 4096;
#pragma unroll
  for (int i = 0; i < 4; ++i) *(f32x4*)&Ub[(tdk + i) * 64 + tdv] = U[i];
  if (t < 64) Spart[(long)(bh * 8 + chunk) * 64 + t] = sacc;
}

__global__ __launch_bounds__(256)
void ctx_reduce(const float* __restrict__ Upart, const float* __restrict__ Spart,
                float* __restrict__ ctx) {
  const int bh = blockIdx.x;
  const int t = threadIdx.x;
  const int tdk = (t & 15) * 4, tdv = (t >> 4) * 4;
  __shared__ float S[64];
  if (t < 64) {
    float s = 0.f;
#pragma unroll
    for (int c = 0; c < 8; ++c) s += Spart[(long)(bh * 8 + c) * 64 + t];
    S[t] = s;
  }
  __syncthreads();
#pragma unroll
  for (int i = 0; i < 4; ++i) {
    const int dk = tdk + i;
    f32x4 u = {};
#pragma unroll
    for (int c = 0; c < 8; ++c)
      u += *(const f32x4*)&Upart[(long)(bh * 8 + c) * 4096 + dk * 64 + tdv];
    u *= (1.f / S[dk]);
    *(f32x4*)&ctx[(long)bh * 4096 + dk * 64 + tdv] = u;
  }
}

// ---------------------------------------------------------------- G matrix
// Gt[b][co][h*64+dk] = sum_dv ctx[b,h,dk,dv] * Wp[co, h*64+dv]   (bf16 out)
__global__ __launch_bounds__(256, 2)
void gstack(const float* __restrict__ ctx, const float* __restrict__ Wp,
            __bf16* __restrict__ Gt) {
  const int cc = blockIdx.x, h = blockIdx.y, b = blockIdx.z;
  const int t = threadIdx.x, lane = t & 63, w = t >> 6;
  const int co0 = cc * 192;
  __shared__ __align__(16) float wf[192 * 64];  // 48 KB

#pragma unroll
  for (int i = 0; i < 12; ++i) {
    const int flat = i * 256 + t;
    const int r = flat >> 4, c4 = flat & 15;
    const f32x4 vsrc = *(const f32x4*)&Wp[(long)(co0 + r) * 768 + h * 64 + c4 * 4];
    *(f32x4*)&wf[r * 64 + c4 * 4] = vsrc;
  }

  f32x4 cx[16];
  const float* crow = ctx + ((long)(b * 12 + h) * 64 + lane) * 64;
#pragma unroll
  for (int j = 0; j < 16; ++j) cx[j] = *(const f32x4*)&crow[j * 4];

  __syncthreads();

  __bf16* gout = Gt + ((long)(b * 768 + co0 + w * 48) * 768) + h * 64 + lane;
  for (int co = 0; co < 48; ++co) {
    const float* wrow = &wf[(w * 48 + co) * 64];
    f32x4 acc = {};
#pragma unroll
    for (int j = 0; j < 16; ++j) acc += cx[j] * *(const f32x4*)&wrow[j * 4];
    const float s = acc[0] + acc[1] + acc[2] + acc[3];
    gout[(long)co * 768] = (__bf16)s;
  }
}

// ---------------------------------------------------------------- launch
extern "C" void kernel_launch(void* const* d_in, const int* in_sizes, int n_in,
                              void* d_out, int out_size, void* d_ws, size_t ws_size,
                              hipStream_t stream) {
  (void)in_sizes; (void)n_in; (void)out_size; (void)ws_size;
  const float* q = (const float*)d_in[0];
  const float* k = (const float*)d_in[1];
  const float* v = (const float*)d_in[2];
  const float* Wq = (const float*)d_in[3];
  const float* Wk = (const float*)d_in[4];
  const float* Wv = (const float*)d_in[5];
  const float* Wp = (const float*)d_in[6];
  const float* bp = (const float*)d_in[7];
  float* out = (float*)d_out;

  const long XE = 32768L * 768L;
  const long WE = 768L * 768L;

  char* ws = (char*)d_ws;
  __bf16* Khb = (__bf16*)ws;                             // XE bf16
  __bf16* Vhb = Khb + XE;                                // XE bf16
  __bf16* Wb = Vhb + XE;                                 // 4*WE bf16: Wk,Wv,(spare),WqT
  __bf16* Gt = Wb + 4 * WE;                              // 8*WE bf16
  __bf16* Mt = Gt + 8 * WE;                              // 8*WE bf16
  float* Upart = (float*)(Mt + 8 * WE);                  // 96*8*4096 f32
  float* Spart = Upart + 96L * 8 * 4096;                 // 96*8*64 f32
  float* ctx = Spart + 96L * 8 * 64;                     // 96*4096 f32

  // 1) weight casts only (activation casts eliminated — AF32 staging)
  cast_kernel<<<576, 256, 0, stream>>>(Wk, Wb + 0 * WE, WE);
  cast_kernel<<<576, 256, 0, stream>>>(Wv, Wb + 1 * WE, WE);
  transpose_cast<<<dim3(24, 24), dim3(32, 8), 0, stream>>>(Wq, Wb + 3 * WE);  // WqT

  // 2) K/V projections (z=2, fp32 A direct): z=0 Kh = k@Wk^T, z=1 Vh = v@Wv^T
  gemm_bt<true><<<dim3(6, 256, 2), 256, 0, stream>>>(k, v, Wb, Khb, nullptr,
                                                     nullptr, 0, WE, XE, 0);

  // 3) softmax-weighted context
  ctx_partial<<<dim3(8, 96), 256, 0, stream>>>(Khb, Vhb, Upart, Spart);
  ctx_reduce<<<96, 256, 0, stream>>>(Upart, Spart, ctx);

  // 4) Gt[b] = (ctx @ Wp-blocks)^T  (fp32 Wp direct)
  gstack<<<dim3(4, 12, 8), 256, 0, stream>>>(ctx, Wp, Gt);

  // 5) Mt[b] : out[m=co, n=ci] = sum_k Gt[co,k] * WqT[ci,k]  (bf16 path)
  gemm_bt<false><<<dim3(6, 6, 8), 256, 0, stream>>>(Gt, nullptr, Wb + 3 * WE, Mt,
                                                    nullptr, nullptr, WE, 0, WE, 0);

  // 6) out[b] = q[b] @ Mt[b]^T + bp  (fp32 A direct, fp32 out)
  gemm_bt<true><<<dim3(6, 256, 1), 256, 0, stream>>>(q, nullptr, Mt, nullptr, out,
                                                     bp, 0, 0, 0, WE);
}